// Round 10
// baseline (794.106 us; speedup 1.0000x reference)
//
#include <hip/hip_runtime.h>
#include <stdint.h>

// Single persistent kernel, dynamic work queue, batch-pipelined:
//   tasks [0,256)      : W reorder fp32 -> Wp[e][p*256+c] bf16       (wcnt -> 256)
//   tasks [256,4352)   : imgT units (b,y,cc): img -> imgT[b][y][x][c] (bcnt[b] -> 512)
//   tasks [4352,5376)  : gemm 128^2 tiles, batch-major; spin until wcnt==256 &&
//                        bcnt[batch]==512, then R5-verified fused-gather MFMA GEMM.
//   pixel (py,px) <-> (o,p): o=(py>>1)+2*(px>>1), p=(py&1)*2+(px&1); k'=p*256+c.

typedef __attribute__((ext_vector_type(8))) short bf16x8;
typedef __attribute__((ext_vector_type(4))) float f32x4;

#define GAS(p) ((const __attribute__((address_space(1))) void*)(p))
#define LAS(p) ((__attribute__((address_space(3))) void*)(p))

struct Flags { int q; int wcnt; int bcnt[8]; int pad[6]; };

__device__ __forceinline__ unsigned short f2bf(float f) {
    union { float f; uint32_t u; } x; x.f = f;
    uint32_t u = x.u;
    uint32_t r = (u + 0x7FFFu + ((u >> 16) & 1u)) >> 16;   // round-nearest-even
    return (unsigned short)r;
}

// ---------------- init: zero queue/counters + zero page ----------------
__global__ __launch_bounds__(256)
void init_kernel(Flags* fl, unsigned short* zp) {
    const int t = threadIdx.x;
    if (t < 16) ((int*)fl)[t] = 0;
    if (t < 128) ((unsigned int*)zp)[t] = 0u;   // 512 B zeros
}

// ---------------- fused persistent kernel ----------------
__global__ __launch_bounds__(256)
void fused_kernel(const float* __restrict__ img, const float* __restrict__ Wf,
                  const float* __restrict__ bias,
                  const int* __restrict__ bidx, const int* __restrict__ pxid,
                  const int* __restrict__ pyid,
                  unsigned short* __restrict__ Wp, const unsigned short* __restrict__ zp,
                  unsigned short* __restrict__ imgT,
                  Flags* fl, float* __restrict__ out)
{
    __shared__ unsigned short sW[8192];   // 16 KB (gemm W tile / prep transpose)
    __shared__ unsigned short sA[8192];   // 16 KB (gemm A tile)
    __shared__ int sTask;

    const int tid = threadIdx.x;

    for (;;) {
        __syncthreads();                   // LDS + sTask reuse boundary
        if (tid == 0) sTask = atomicAdd(&fl->q, 1);
        __syncthreads();
        const int t = sTask;
        if (t >= 5376) break;

        if (t < 256) {
            // ---- W unit: 4 e-rows -> Wp[e][p*256+c] ----
            #pragma unroll
            for (int r = 0; r < 4; ++r) {
                const int e = t * 4 + r;
                const int c = tid;
                float4 w4 = *(const float4*)&Wf[(size_t)e * 1024 + c * 4];
                Wp[e * 1024 + 0 * 256 + c] = f2bf(w4.x);
                Wp[e * 1024 + 1 * 256 + c] = f2bf(w4.y);
                Wp[e * 1024 + 2 * 256 + c] = f2bf(w4.z);
                Wp[e * 1024 + 3 * 256 + c] = f2bf(w4.w);
            }
            __syncthreads();               // all stores issued & drained (vmcnt0)
            __threadfence();
            if (tid == 0)
                __hip_atomic_fetch_add(&fl->wcnt, 1, __ATOMIC_RELEASE,
                                       __HIP_MEMORY_SCOPE_AGENT);
        } else if (t < 4352) {
            // ---- imgT unit: (b, y, cc-chunk of 64), float4 reads + LDS transpose ----
            const int u  = t - 256;
            const int cc = u & 3;
            const int y  = (u >> 2) & 127;
            const int b  = u >> 9;
            const int xq = tid & 31;       // x = xq*4 + jj
            const int ch = tid >> 5;       // 0..7
            unsigned int* sU = (unsigned int*)sW;
            const size_t pl = ((size_t)b * 256 + cc * 64) * 16384 + (size_t)y * 128;
            #pragma unroll
            for (int it = 0; it < 4; ++it) {
                const int cp = it * 8 + ch;     // c-pair 0..31
                const float4 v0 = *(const float4*)&img[pl + (size_t)(2 * cp)     * 16384 + xq * 4];
                const float4 v1 = *(const float4*)&img[pl + (size_t)(2 * cp + 1) * 16384 + xq * 4];
                const float a0[4] = {v0.x, v0.y, v0.z, v0.w};
                const float a1[4] = {v1.x, v1.y, v1.z, v1.w};
                #pragma unroll
                for (int jj = 0; jj < 4; ++jj) {
                    const int x = xq * 4 + jj;
                    const unsigned int pk = (unsigned)f2bf(a0[jj]) | ((unsigned)f2bf(a1[jj]) << 16);
                    sU[x * 32 + (cp ^ (x & 31))] = pk;
                }
            }
            __syncthreads();
            unsigned short* ob = imgT + (((size_t)b * 128 + y) * 128) * 256 + cc * 64;
            #pragma unroll
            for (int jj = 0; jj < 16; ++jj) {
                const int oo = tid + 256 * jj;
                const int xx = oo >> 5;
                const int c2 = oo & 31;
                const unsigned int pk = sU[xx * 32 + (c2 ^ (xx & 31))];
                *(unsigned int*)&ob[(size_t)xx * 256 + c2 * 2] = pk;
            }
            __syncthreads();               // drain stores (vmcnt0 before barrier)
            __threadfence();
            if (tid == 0)
                __hip_atomic_fetch_add(&fl->bcnt[b], 1, __ATOMIC_RELEASE,
                                       __HIP_MEMORY_SCOPE_AGENT);
        } else {
            // ---- gemm tile (R5 structure): tl batch-major ----
            const int tl = t - 4352;       // 0..1023
            const int b  = tl >> 7;        // batch
            const int rr = tl & 127;
            const int et = rr & 7;         // 8 e-tiles of 128
            const int gl = rr >> 3;        // 0..15
            const int o  = gl >> 2;        // offset
            const int n0 = (gl & 3) * 128;
            const int g  = b * 4 + o;
            const int e0 = et * 128;

            // spin until W and this batch's imgT are ready
            if (tid == 0) {
                while (__hip_atomic_load(&fl->wcnt, __ATOMIC_ACQUIRE,
                                         __HIP_MEMORY_SCOPE_AGENT) < 256) {}
                while (__hip_atomic_load(&fl->bcnt[b], __ATOMIC_ACQUIRE,
                                         __HIP_MEMORY_SCOPE_AGENT) < 512) {}
            }
            __syncthreads();

            const int lane = tid & 63;
            const int wid  = tid >> 6;
            const int wr   = wid >> 1;
            const int wc   = wid & 1;

            const int row0 = tid >> 3;                 // 0..31
            const int cg   = (tid & 7) ^ (row0 & 7);   // (row&7)==(row0&7), 32r%8==0
            int ay[4], ax[4];
            size_t apl[4];
            #pragma unroll
            for (int r = 0; r < 4; ++r) {
                const int row = row0 + 32 * r;
                const int gi = b * 512 + n0 + row;
                apl[r] = (size_t)bidx[gi] * (128 * 128 * 256);
                ay[r] = 2 * pyid[gi] - 1 + (o & 1) * 2;
                ax[r] = 2 * pxid[gi] - 1 + (o >> 1) * 2;
            }

            const f32x4 fzero = {0.f, 0.f, 0.f, 0.f};
            f32x4 acc[4][4];
            #pragma unroll
            for (int m = 0; m < 4; ++m)
                #pragma unroll
                for (int nf = 0; nf < 4; ++nf) acc[m][nf] = fzero;

            for (int kc = 0; kc < 16; ++kc) {
                if (kc) __syncthreads();
                const int p   = kc >> 2;
                const int csh = (kc & 3) * 64;
                #pragma unroll
                for (int r = 0; r < 4; ++r) {
                    const int i   = r * 256 + tid;
                    const int row = row0 + 32 * r;
                    const unsigned short* gw = Wp + (size_t)(e0 + row) * 1024 + kc * 64 + cg * 8;
                    __builtin_amdgcn_global_load_lds(GAS(gw), LAS(&sW[i * 8]), 16, 0, 0);
                    const int yy = ay[r] + (p >> 1);
                    const int xx = ax[r] + (p & 1);
                    const unsigned short* ga =
                        ((unsigned)yy < 128u && (unsigned)xx < 128u)
                            ? imgT + apl[r] + ((size_t)(yy * 128 + xx)) * 256 + csh + cg * 8
                            : zp + cg * 8;
                    __builtin_amdgcn_global_load_lds(GAS(ga), LAS(&sA[i * 8]), 16, 0, 0);
                }
                asm volatile("s_waitcnt vmcnt(0)" ::: "memory");
                __syncthreads();

                #pragma unroll
                for (int ks = 0; ks < 2; ++ks) {
                    bf16x8 af[4], bfr[4];
                    #pragma unroll
                    for (int m = 0; m < 4; ++m) {
                        const int row = wr * 64 + m * 16 + (lane & 15);
                        const int cl  = (ks * 4 + (lane >> 4)) ^ (row & 7);
                        af[m] = *(const bf16x8*)&sW[row * 64 + cl * 8];
                    }
                    #pragma unroll
                    for (int nf = 0; nf < 4; ++nf) {
                        const int row = wc * 64 + nf * 16 + (lane & 15);
                        const int cl  = (ks * 4 + (lane >> 4)) ^ (row & 7);
                        bfr[nf] = *(const bf16x8*)&sA[row * 64 + cl * 8];
                    }
                    __builtin_amdgcn_s_setprio(1);
                    #pragma unroll
                    for (int m = 0; m < 4; ++m)
                        #pragma unroll
                        for (int nf = 0; nf < 4; ++nf)
                            acc[m][nf] = __builtin_amdgcn_mfma_f32_16x16x32_bf16(
                                af[m], bfr[nf], acc[m][nf], 0, 0, 0);
                    __builtin_amdgcn_s_setprio(0);
                }
            }

            const int erow_l = (lane >> 4) * 4;
            const int ncol_l = lane & 15;
            #pragma unroll
            for (int m = 0; m < 4; ++m) {
                #pragma unroll
                for (int nf = 0; nf < 4; ++nf) {
                    const int nn = n0 + wc * 64 + nf * 16 + ncol_l;
                    #pragma unroll
                    for (int reg = 0; reg < 4; ++reg) {
                        const int e = e0 + wr * 64 + m * 16 + erow_l + reg;
                        out[((size_t)g * 1024 + e) * 512 + nn] = acc[m][nf][reg] + bias[e];
                    }
                }
            }
        }
    }
}

extern "C" void kernel_launch(void* const* d_in, const int* in_sizes, int n_in,
                              void* d_out, int out_size, void* d_ws, size_t ws_size,
                              hipStream_t stream) {
    const float* img  = (const float*)d_in[0];
    const float* Wf   = (const float*)d_in[1];
    const float* bias = (const float*)d_in[2];
    const int*   bidx = (const int*)d_in[3];
    const int*   pxid = (const int*)d_in[4];
    const int*   pyid = (const int*)d_in[5];
    float* out = (float*)d_out;

    unsigned short* Wp   = (unsigned short*)((char*)d_ws + (32u << 20));  // 2 MiB
    unsigned short* zp   = (unsigned short*)((char*)d_ws + (36u << 20));  // 512 B zeros
    Flags*          fl   = (Flags*)((char*)d_ws + (40u << 20));
    unsigned short* imgT = (unsigned short*)((char*)d_ws + (64u << 20));  // 64 MiB

    hipLaunchKernelGGL(init_kernel, dim3(1), dim3(256), 0, stream, fl, zp);
    hipLaunchKernelGGL(fused_kernel, dim3(1024), dim3(256), 0, stream,
                       img, Wf, bias, bidx, pxid, pyid, Wp, zp, imgT, fl, out);
}

// Round 11
// 94.690 us; speedup vs baseline: 8.3864x; 8.3864x over previous
//
#include <hip/hip_runtime.h>
#include <stdint.h>

// Pipeline (k' = (ky*2+kx)*256 + c ordering for the GEMM K axis):
//   0. prep : blocks 0..511    -> W fp32 -> Wq in GEMM-staging order (chunk-major) bf16
//             blocks 512..4607 -> img (8,256,128,128) fp32 -> imgT[b][y][x][c] bf16
//   1. gemm : 256x256-tile 8-wave MFMA GEMM, 8-phase schedule, counted vmcnt(4)
//             (never 0 in loop), A gathered in-staging from imgT per keypoint.
//      pixel (py,px) <-> (o,p): o=(py>>1)+2*(px>>1), p=(py&1)*2+(px&1)
// R10 = R7 (best, 79.7us) + nontemporal hints on img reads / imgT writes / out writes
// (keep L2 free for W-panel + A-row reuse; R9's persistent-kernel overlap abandoned:
//  agent-scope acquire/release fences invalidate/writeback whole L2 -> 10x regression).

typedef __attribute__((ext_vector_type(8))) short bf16x8;
typedef __attribute__((ext_vector_type(4))) float f32x4;

#define GAS(p) ((const __attribute__((address_space(1))) void*)(p))
#define LAS(p) ((__attribute__((address_space(3))) void*)(p))

__device__ __forceinline__ unsigned short f2bf(float f) {
    union { float f; uint32_t u; } x; x.f = f;
    uint32_t u = x.u;
    uint32_t r = (u + 0x7FFFu + ((u >> 16) & 1u)) >> 16;   // round-nearest-even
    return (unsigned short)r;
}

// ---------------- Stage 0: fused W-reorder (staging order) + img transpose ----------------
__global__ __launch_bounds__(256)
void prep_kernel(const float* __restrict__ img, const float* __restrict__ Wf,
                 unsigned short* __restrict__ Wq, unsigned short* __restrict__ zp,
                 unsigned short* __restrict__ imgT) {
    __shared__ unsigned short sT[8192];
    const int blk = blockIdx.x;
    const int tid = threadIdx.x;

    if (blk < 512) {                        // ---- Wq: one thread = 8 k's of one (et,j,h,chunk,row)
        if (blk == 0 && tid < 32) {
            uint4 z = {0, 0, 0, 0};
            ((uint4*)zp)[tid] = z;          // 512 B zeros for OOB staging
        }
        const int t  = blk * 256 + tid;     // 0..131071
        const int et = t >> 15;
        const int r1 = t & 32767;
        const int j  = r1 >> 11;
        const int r2 = r1 & 2047;
        const int h  = r2 >> 10;
        const int r3 = r2 & 1023;
        const int chunk = r3 >> 8;
        const int row   = r3 & 255;
        const int e  = et * 256 + row;
        const int kb = j * 64 + h * 32 + chunk * 8;
        unsigned short v[8];
        #pragma unroll
        for (int kk = 0; kk < 8; ++kk) {
            const int k = kb + kk;          // k' in [0,1024)
            const int c = k & 255;
            const int p = k >> 8;
            v[kk] = f2bf(Wf[(size_t)e * 1024 + c * 4 + p]);
        }
        *(uint4*)&Wq[(size_t)t * 8] = *(const uint4*)v;
        return;
    }

    // ---- imgt: block = (b, y, c-chunk of 64); nontemporal f32x4 reads + nt uint writes ----
    const int ib = blk - 512;               // 0..4095
    const int cc = ib & 3;
    const int y  = (ib >> 2) & 127;
    const int b  = ib >> 9;
    const int xq = tid & 31;                // x-quad: x = xq*4 + jj
    const int ch = tid >> 5;                // 0..7 (c-pair subgroup)
    unsigned int* sU = (unsigned int*)sT;
    const size_t pl = ((size_t)b * 256 + cc * 64) * 16384 + (size_t)y * 128;
    #pragma unroll
    for (int it = 0; it < 4; ++it) {
        const int cp = it * 8 + ch;         // c-pair 0..31
        const f32x4 v0 = __builtin_nontemporal_load(
            (const f32x4*)&img[pl + (size_t)(2 * cp)     * 16384 + xq * 4]);
        const f32x4 v1 = __builtin_nontemporal_load(
            (const f32x4*)&img[pl + (size_t)(2 * cp + 1) * 16384 + xq * 4]);
        #pragma unroll
        for (int jj = 0; jj < 4; ++jj) {
            const int x = xq * 4 + jj;
            const unsigned int pk = (unsigned)f2bf(v0[jj]) | ((unsigned)f2bf(v1[jj]) << 16);
            sU[x * 32 + (cp ^ (x & 31))] = pk;
        }
    }
    __syncthreads();
    unsigned short* ob = imgT + (((size_t)b * 128 + y) * 128) * 256 + cc * 64;
    #pragma unroll
    for (int jj = 0; jj < 16; ++jj) {
        const int oo = tid + 256 * jj;      // 0..4095
        const int xx = oo >> 5;
        const int c2 = oo & 31;
        const unsigned int pk = sU[xx * 32 + (c2 ^ (xx & 31))];
        __builtin_nontemporal_store(pk, (unsigned int*)&ob[(size_t)xx * 256 + c2 * 2]);
    }
}

// ---------------- Stage 1: fused-gather 256^2 8-phase MFMA GEMM ----------------
// 256 blocks (1/CU), 512 threads (8 waves 2m x 4n). 16 K-tiles of BK=64,
// each tile = 2 K-halves; per half: vmcnt(4)+barrier, issue next-tile half's
// 4 staging insts, ds_read af[8] (W, conflict-free), then 2 phases of
// {ds_read bf[2] (A), setprio, 16 MFMA, setprio}. In-flight 4-8, never 0.
__global__ __launch_bounds__(512, 1)
void gemm_kernel(const unsigned short* __restrict__ Wq,
                 const unsigned short* __restrict__ imgT,
                 const unsigned short* __restrict__ zp,
                 const int* __restrict__ bidx,
                 const int* __restrict__ pxid,
                 const int* __restrict__ pyid,
                 const float* __restrict__ bias,
                 float* __restrict__ out)
{
    const int orig = blockIdx.x;            // 256
    const int xcd  = orig & 7;
    const int s    = orig >> 3;             // 0..31
    const int gnt  = xcd * 8 + (s >> 2);    // 64 gn-tiles of 256; e-siblings share XCD
    const int et   = s & 3;                 // 4 e-tiles of 256
    const int e0   = et * 256;
    const int g    = gnt >> 1;
    const int n0   = (gnt & 1) * 256;
    const int b = g >> 2, o = g & 3;

    const int tid  = threadIdx.x;
    const int lane = tid & 63;
    const int wid  = tid >> 6;
    const int wm   = wid >> 2;              // 0..1 -> e rows wm*128
    const int wn   = wid & 3;               // 0..3 -> n cols wn*64

    __shared__ unsigned short sW[2 * 16384]; // [buf][h:2][chunk:4][row:256][8]
    __shared__ unsigned short sA[2 * 16384]; // [buf][h:2][row:256][slot:4][8]

    // ---- A stage descriptors: thread -> rows u*128 + tid/4, 16B chunk (tid&3) ----
    int ayv[2], axv[2];
    size_t apl[2];
    #pragma unroll
    for (int u = 0; u < 2; ++u) {
        const int row = u * 128 + (tid >> 2);
        const int gi = b * 512 + n0 + row;
        apl[u] = (size_t)bidx[gi] * (128 * 128 * 256);
        ayv[u] = 2 * pyid[gi] - 1 + (o & 1) * 2;   // + (p>>1) at stage time
        axv[u] = 2 * pxid[gi] - 1 + (o >> 1) * 2;  // + (p&1)
    }
    const int aswz = (((tid & 3) ^ ((tid >> 3) & 3))) * 8;  // pre-swizzled chunk (shorts)
    const unsigned short* wq_base = Wq + (size_t)et * 262144 + tid * 8;

    f32x4 acc[8][4];
    #pragma unroll
    for (int m = 0; m < 8; ++m)
        #pragma unroll
        for (int nf = 0; nf < 4; ++nf) acc[m][nf] = (f32x4){0.f, 0.f, 0.f, 0.f};

    auto stageHalf = [&](int j, int h, int buf) {
        // W: 2 insts, fully coalesced from Wq staging order
        #pragma unroll
        for (int u = 0; u < 2; ++u) {
            const unsigned short* src = wq_base + (size_t)(j * 2 + h) * 8192 + u * 4096;
            __builtin_amdgcn_global_load_lds(GAS(src),
                LAS(&sW[buf * 16384 + h * 8192 + u * 4096 + tid * 8]), 16, 0, 0);
        }
        // A: 2 insts, 64B-aligned segments per keypoint row, swizzled source
        const int p = j >> 2;
        const int csh = (j & 3) * 64 + h * 32 + aswz;
        #pragma unroll
        for (int u = 0; u < 2; ++u) {
            const int yy = ayv[u] + (p >> 1);
            const int xx = axv[u] + (p & 1);
            const unsigned short* src =
                ((unsigned)yy < 128u && (unsigned)xx < 128u)
                    ? imgT + apl[u] + ((size_t)(yy * 128 + xx)) * 256 + csh
                    : zp + aswz;
            __builtin_amdgcn_global_load_lds(GAS(src),
                LAS(&sA[buf * 16384 + h * 8192 + u * 4096 + tid * 8]), 16, 0, 0);
        }
    };

    // prologue: tile 0 fully staged (8 insts in flight)
    stageHalf(0, 0, 0);
    stageHalf(0, 1, 0);

    for (int j = 0; j < 16; ++j) {
        const int buf = j & 1;
        #pragma unroll
        for (int h = 0; h < 2; ++h) {
            // complete the oldest half (tile j, half h); keep the rest in flight
            if (j == 15 && h == 1) { asm volatile("s_waitcnt vmcnt(0)" ::: "memory"); }
            else                   { asm volatile("s_waitcnt vmcnt(4)" ::: "memory"); }
            __builtin_amdgcn_s_barrier();
            if (j < 15) stageHalf(j + 1, h, buf ^ 1);   // 4 insts into the other dbuf

            // W fragments for this K-half (reused across both n-half phases)
            bf16x8 af[8];
            {
                const int chunk = lane >> 4;
                const int rb = wm * 128 + (lane & 15);
                #pragma unroll
                for (int m = 0; m < 8; ++m)
                    af[m] = *(const bf16x8*)&sW[buf * 16384 + h * 8192 + chunk * 2048 + (rb + m * 16) * 8];
            }
            #pragma unroll
            for (int nh = 0; nh < 2; ++nh) {
                bf16x8 bfr[2];
                #pragma unroll
                for (int nn = 0; nn < 2; ++nn) {
                    const int row = wn * 64 + (nh * 2 + nn) * 16 + (lane & 15);
                    const int perm = (lane >> 4) ^ ((row >> 1) & 3);
                    bfr[nn] = *(const bf16x8*)&sA[buf * 16384 + h * 8192 + row * 32 + perm * 8];
                }
                __builtin_amdgcn_s_setprio(1);
                #pragma unroll
                for (int m = 0; m < 8; ++m)
                    #pragma unroll
                    for (int nn = 0; nn < 2; ++nn)
                        acc[m][nh * 2 + nn] = __builtin_amdgcn_mfma_f32_16x16x32_bf16(
                            af[m], bfr[nn], acc[m][nh * 2 + nn], 0, 0, 0);
                __builtin_amdgcn_s_setprio(0);
            }
        }
    }

    // ---- epilogue: D row(e) = (lane>>4)*4+reg, col(n) = lane&15; nt stores ----
    #pragma unroll
    for (int m = 0; m < 8; ++m) {
        const int eb = e0 + wm * 128 + m * 16 + (lane >> 4) * 4;
        float bv[4];
        #pragma unroll
        for (int reg = 0; reg < 4; ++reg) bv[reg] = bias[eb + reg];
        #pragma unroll
        for (int nf = 0; nf < 4; ++nf) {
            const int nn = n0 + wn * 64 + nf * 16 + (lane & 15);
            #pragma unroll
            for (int reg = 0; reg < 4; ++reg)
                __builtin_nontemporal_store(acc[m][nf][reg] + bv[reg],
                    &out[((size_t)g * 1024 + eb + reg) * 512 + nn]);
        }
    }
}

extern "C" void kernel_launch(void* const* d_in, const int* in_sizes, int n_in,
                              void* d_out, int out_size, void* d_ws, size_t ws_size,
                              hipStream_t stream) {
    const float* img  = (const float*)d_in[0];
    const float* Wf   = (const float*)d_in[1];
    const float* bias = (const float*)d_in[2];
    const int*   bidx = (const int*)d_in[3];
    const int*   pxid = (const int*)d_in[4];
    const int*   pyid = (const int*)d_in[5];
    float* out = (float*)d_out;

    unsigned short* Wq   = (unsigned short*)((char*)d_ws + (32u << 20));  // 2 MiB
    unsigned short* zp   = (unsigned short*)((char*)d_ws + (36u << 20));  // 512 B zeros
    unsigned short* imgT = (unsigned short*)((char*)d_ws + (64u << 20));  // 64 MiB

    hipLaunchKernelGGL(prep_kernel, dim3(4608), dim3(256), 0, stream,
                       img, Wf, Wq, zp, imgT);
    hipLaunchKernelGGL(gemm_kernel, dim3(256), dim3(512), 0, stream,
                       Wq, imgT, zp, bidx, pxid, pyid, bias, out);
}

// Round 12
// 92.410 us; speedup vs baseline: 8.5932x; 1.0247x over previous
//
#include <hip/hip_runtime.h>
#include <stdint.h>

// Pipeline (k' = (ky*2+kx)*256 + c ordering for the GEMM K axis):
//   0. prep : blocks 0..511    -> W fp32 -> Wq bf16 in GEMM LDS-staging order:
//                                [tile:32][slot:4096] where slot = kc*1024+e (16B units)
//             blocks 512..4607 -> img (8,256,128,128) fp32 -> imgT[b][y][x][c] bf16
//   1. gemm : BM=1024 (ALL e) x BN=64 tile per block -> A staged EXACTLY ONCE
//             (1x redundancy, was 4x). W streamed dense from L2-resident Wq.
//             BK=32, W double-buffered (2x64KB), A K-64 pairs triple-buffered
//             (3x4KB) staged 4 tiles ahead. Counted vmcnt (8/9), 0 only at drain.
//      pixel (py,px) <-> (o,p): o=(py>>1)+2*(px>>1), p=(py&1)*2+(px&1)

typedef __attribute__((ext_vector_type(8))) short bf16x8;
typedef __attribute__((ext_vector_type(4))) float f32x4;

#define GAS(p) ((const __attribute__((address_space(1))) void*)(p))
#define LAS(p) ((__attribute__((address_space(3))) void*)(p))

__device__ __forceinline__ unsigned short f2bf(float f) {
    union { float f; uint32_t u; } x; x.f = f;
    uint32_t u = x.u;
    uint32_t r = (u + 0x7FFFu + ((u >> 16) & 1u)) >> 16;   // round-nearest-even
    return (unsigned short)r;
}

// ---------------- Stage 0: W-reorder (LDS-staging order) + img transpose ----------------
__global__ __launch_bounds__(256)
void prep_kernel(const float* __restrict__ img, const float* __restrict__ Wf,
                 unsigned short* __restrict__ Wq, unsigned short* __restrict__ zp,
                 unsigned short* __restrict__ imgT) {
    __shared__ unsigned short sT[8192];
    const int blk = blockIdx.x;
    const int tid = threadIdx.x;

    if (blk < 512) {                        // ---- Wq: 131072 16B-groups
        if (blk == 0 && tid < 32) {
            uint4 z = {0, 0, 0, 0};
            ((uint4*)zp)[tid] = z;          // 512 B zeros for OOB staging
        }
        const int t    = blk * 256 + tid;   // 0..131071
        const int tile = t >> 12;           // K-tile of 32
        const int r    = t & 4095;          // slot = kc*1024 + e
        const int kc   = r >> 10;
        const int e    = r & 1023;
        const int kb   = tile * 32 + kc * 8;
        unsigned short v[8];
        #pragma unroll
        for (int kk = 0; kk < 8; ++kk) {
            const int k = kb + kk;          // k' in [0,1024)
            const int c = k & 255;
            const int p = k >> 8;
            v[kk] = f2bf(Wf[(size_t)e * 1024 + c * 4 + p]);
        }
        *(uint4*)&Wq[(size_t)t * 8] = *(const uint4*)v;
        return;
    }

    // ---- imgt: block = (b, y, c-chunk of 64); float4-vectorized reads ----
    const int ib = blk - 512;               // 0..4095
    const int cc = ib & 3;
    const int y  = (ib >> 2) & 127;
    const int b  = ib >> 9;
    const int xq = tid & 31;                // x-quad: x = xq*4 + jj
    const int ch = tid >> 5;                // 0..7 (c-pair subgroup)
    unsigned int* sU = (unsigned int*)sT;
    const size_t pl = ((size_t)b * 256 + cc * 64) * 16384 + (size_t)y * 128;
    #pragma unroll
    for (int it = 0; it < 4; ++it) {
        const int cp = it * 8 + ch;         // c-pair 0..31
        const float4 v0 = *(const float4*)&img[pl + (size_t)(2 * cp)     * 16384 + xq * 4];
        const float4 v1 = *(const float4*)&img[pl + (size_t)(2 * cp + 1) * 16384 + xq * 4];
        const float a0[4] = {v0.x, v0.y, v0.z, v0.w};
        const float a1[4] = {v1.x, v1.y, v1.z, v1.w};
        #pragma unroll
        for (int jj = 0; jj < 4; ++jj) {
            const int x = xq * 4 + jj;
            const unsigned int pk = (unsigned)f2bf(a0[jj]) | ((unsigned)f2bf(a1[jj]) << 16);
            sU[x * 32 + (cp ^ (x & 31))] = pk;
        }
    }
    __syncthreads();
    unsigned short* ob = imgT + (((size_t)b * 128 + y) * 128) * 256 + cc * 64;
    #pragma unroll
    for (int jj = 0; jj < 16; ++jj) {
        const int oo = tid + 256 * jj;      // 0..4095
        const int xx = oo >> 5;
        const int c2 = oo & 31;
        const unsigned int pk = sU[xx * 32 + (c2 ^ (xx & 31))];
        *(unsigned int*)&ob[(size_t)xx * 256 + c2 * 2] = pk;
    }
}

// ---------------- Stage 1: BM=1024 x BN=64 fused-gather MFMA GEMM ----------------
// 256 blocks (1/CU), 512 threads (8 waves, wave w -> e rows w*128..+128, all 64 n).
// 32 K-tiles of 32. W: 8 insts/thread/tile, dbuf. A: 1 inst/thread per K-64 pair,
// 3 bufs, staged 4 tiles ahead. vmcnt: even tile 8, odd 9, last 0.
__global__ __launch_bounds__(512, 1)
void gemm_kernel(const unsigned short* __restrict__ Wq,
                 const unsigned short* __restrict__ imgT,
                 const unsigned short* __restrict__ zp,
                 const int* __restrict__ bidx,
                 const int* __restrict__ pxid,
                 const int* __restrict__ pyid,
                 const float* __restrict__ bias,
                 float* __restrict__ out)
{
    const int tile = blockIdx.x;            // 0..255
    const int g    = tile >> 3;             // 32 (b,off) groups
    const int n0   = (tile & 7) * 64;       // 64-keypoint window
    const int b = g >> 2, o = g & 3;

    const int tid  = threadIdx.x;
    const int lane = tid & 63;
    const int w    = tid >> 6;              // wave id 0..7 -> e base w*128

    __shared__ unsigned short sW[2][32768]; // [buf][slot: kc*1024+e][8]  128 KB
    __shared__ unsigned short sA[3][4096];  // [buf][row:64][slot:8][8]    24 KB

    // ---- A descriptor: thread -> row tid>>3, LDS slot tid&7, XOR-source ----
    const int arow = tid >> 3;              // 0..63
    const int sg   = (tid & 7) ^ (arow & 7);    // global 16B-slot fetched
    const int gi   = b * 512 + n0 + arow;
    const size_t apl = (size_t)bidx[gi] * (128 * 128 * 256);
    const int ay0 = 2 * pyid[gi] - 1 + (o & 1) * 2;
    const int ax0 = 2 * pxid[gi] - 1 + (o >> 1) * 2;

    auto stageA = [&](int pp, int abuf) {   // pair pp: k in [64pp, 64pp+64)
        const int p  = pp >> 2;
        const int yy = ay0 + (p >> 1);
        const int xx = ax0 + (p & 1);
        const unsigned short* src =
            ((unsigned)yy < 128u && (unsigned)xx < 128u)
                ? imgT + apl + ((size_t)(yy * 128 + xx)) * 256 + (pp & 3) * 64 + sg * 8
                : zp + sg * 8;
        __builtin_amdgcn_global_load_lds(GAS(src), LAS(&sA[abuf][tid * 8]), 16, 0, 0);
    };
    auto stageW = [&](int j, int wbuf) {    // 8 fully-coalesced insts
        const unsigned short* base = Wq + (size_t)j * 32768 + tid * 8;
        #pragma unroll
        for (int u = 0; u < 8; ++u)
            __builtin_amdgcn_global_load_lds(GAS(base + u * 4096),
                LAS(&sW[wbuf][u * 4096 + tid * 8]), 16, 0, 0);
    };

    f32x4 acc[8][4];
    #pragma unroll
    for (int m = 0; m < 8; ++m)
        #pragma unroll
        for (int nf = 0; nf < 4; ++nf) acc[m][nf] = (f32x4){0.f, 0.f, 0.f, 0.f};

    // prologue (order matters for vmcnt math: A first)
    stageA(0, 0); stageA(1, 1); stageW(0, 0); stageW(1, 1);

    int prd = 0;   // A read buf = (j>>1)%3
    int pst = 2;   // A stage buf = ((j>>1)+2)%3
    #pragma unroll 2
    for (int j = 0; j < 32; ++j) {
        // complete tile j's W (and its A pair, staged earlier); keep rest in flight
        if (j == 31)    { asm volatile("s_waitcnt vmcnt(0)" ::: "memory"); }
        else if (j & 1) { asm volatile("s_waitcnt vmcnt(9)" ::: "memory"); }
        else            { asm volatile("s_waitcnt vmcnt(8)" ::: "memory"); }
        __builtin_amdgcn_s_barrier();
        if (!(j & 1) && j <= 26) {          // deep A prefetch: pair (j>>1)+2
            stageA((j >> 1) + 2, pst);
            pst = (pst == 2) ? 0 : pst + 1;
        }

        const int wbuf = j & 1;
        const int kc = lane >> 4;           // 8-k chunk within tile
        bf16x8 af[8];
        #pragma unroll
        for (int m = 0; m < 8; ++m) {
            const int e = w * 128 + m * 16 + (lane & 15);
            af[m] = *(const bf16x8*)&sW[wbuf][(kc * 1024 + e) * 8];
        }
        #pragma unroll
        for (int nf = 0; nf < 4; ++nf) {
            const int row = nf * 16 + (lane & 15);
            const int sl  = (wbuf * 4 + kc) ^ (row & 7);   // half sel = j&1
            const bf16x8 bfr = *(const bf16x8*)&sA[prd][(row * 8 + sl) * 8];
            __builtin_amdgcn_s_setprio(1);
            #pragma unroll
            for (int m = 0; m < 8; ++m)
                acc[m][nf] = __builtin_amdgcn_mfma_f32_16x16x32_bf16(
                    af[m], bfr, acc[m][nf], 0, 0, 0);
            __builtin_amdgcn_s_setprio(0);
        }
        __builtin_amdgcn_s_barrier();       // all waves done with sW[wbuf]
        if (j & 1) prd = (prd == 2) ? 0 : prd + 1;
        if (j <= 29) stageW(j + 2, wbuf);   // (j+2)&1 == wbuf
    }

    // ---- epilogue: D row(e) = (lane>>4)*4+reg, col(n) = lane&15 ----
    #pragma unroll
    for (int m = 0; m < 8; ++m) {
        const int eb = w * 128 + m * 16 + (lane >> 4) * 4;
        float bv[4];
        #pragma unroll
        for (int reg = 0; reg < 4; ++reg) bv[reg] = bias[eb + reg];
        #pragma unroll
        for (int nf = 0; nf < 4; ++nf) {
            const int nn = n0 + nf * 16 + (lane & 15);
            #pragma unroll
            for (int reg = 0; reg < 4; ++reg)
                out[((size_t)g * 1024 + eb + reg) * 512 + nn] = acc[m][nf][reg] + bv[reg];
        }
    }
}

extern "C" void kernel_launch(void* const* d_in, const int* in_sizes, int n_in,
                              void* d_out, int out_size, void* d_ws, size_t ws_size,
                              hipStream_t stream) {
    const float* img  = (const float*)d_in[0];
    const float* Wf   = (const float*)d_in[1];
    const float* bias = (const float*)d_in[2];
    const int*   bidx = (const int*)d_in[3];
    const int*   pxid = (const int*)d_in[4];
    const int*   pyid = (const int*)d_in[5];
    float* out = (float*)d_out;

    unsigned short* Wq   = (unsigned short*)((char*)d_ws + (32u << 20));  // 2 MiB
    unsigned short* zp   = (unsigned short*)((char*)d_ws + (36u << 20));  // 512 B zeros
    unsigned short* imgT = (unsigned short*)((char*)d_ws + (64u << 20));  // 64 MiB

    hipLaunchKernelGGL(prep_kernel, dim3(4608), dim3(256), 0, stream,
                       img, Wf, Wq, zp, imgT);
    hipLaunchKernelGGL(gemm_kernel, dim3(256), dim3(512), 0, stream,
                       Wq, imgT, zp, bidx, pxid, pyid, bias, out);
}